// Round 2
// baseline (146.350 us; speedup 1.0000x reference)
//
#include <hip/hip_runtime.h>
#include <math.h>

#define V 8192
#define D 128
#define NH 8
#define HD 16
#define SEQ 128
#define HID 341
#define EPS 1e-6f

__device__ __forceinline__ float sigm(float x) { return 1.0f / (1.0f + __expf(-x)); }

// 256-thread block-wide sum. scratch >= 4 floats. 2 barriers.
__device__ __forceinline__ float block_sum256(float v, float* scratch) {
    #pragma unroll
    for (int m = 32; m > 0; m >>= 1) v += __shfl_xor(v, m);
    if ((threadIdx.x & 63) == 0) scratch[threadIdx.x >> 6] = v;
    __syncthreads();
    float s = (scratch[0] + scratch[1]) + (scratch[2] + scratch[3]);
    __syncthreads();
    return s;
}

// K1: embed + rms + qkv + rope. grid = SEQ + 256 (warm blocks), block=256
__global__ __launch_bounds__(256, 1) void k_embed_qkv(
    const int* __restrict__ idx, const float* __restrict__ w_raw,
    const float* __restrict__ wq, const float* __restrict__ wk,
    const float* __restrict__ wv, const float* __restrict__ n1w,
    const float* __restrict__ w1, const float* __restrict__ w3,
    const float* __restrict__ w2, const float* __restrict__ wo,
    float* __restrict__ x, float* __restrict__ q, float* __restrict__ k,
    float* __restrict__ v, float* __restrict__ sink) {
    int t = threadIdx.x;
    if (blockIdx.x >= SEQ) {
        // L3-warm: stream every weight once (w_raw 4MB + layers ~1.8MB)
        int g = (blockIdx.x - SEQ) * 256 + t;  // 0..65535
        float acc = 0.f;
        const float4* p = (const float4*)w_raw;  // 262144 float4
        for (int i = g; i < 262144; i += 65536) {
            float4 u = p[i];
            acc += u.x + u.y + u.z + u.w;
        }
        p = (const float4*)w1;  // 21824 float4 (both layers)
        if (g < 21824) { float4 u = p[g]; acc += u.x + u.y + u.z + u.w; }
        p = (const float4*)w3;
        if (g < 21824) { float4 u = p[g]; acc += u.x + u.y + u.z + u.w; }
        p = (const float4*)w2;
        if (g < 21824) { float4 u = p[g]; acc += u.x + u.y + u.z + u.w; }
        p = (const float4*)wq;  // 8192 float4 (both layers)
        if (g < 8192) { float4 u = p[g]; acc += u.x + u.y + u.z + u.w; }
        p = (const float4*)wk;
        if (g < 8192) { float4 u = p[g]; acc += u.x + u.y + u.z + u.w; }
        p = (const float4*)wv;
        if (g < 8192) { float4 u = p[g]; acc += u.x + u.y + u.z + u.w; }
        p = (const float4*)wo;
        if (g < 8192) { float4 u = p[g]; acc += u.x + u.y + u.z + u.w; }
        if (acc == 1234.5678f) sink[0] = acc;  // never true; defeats DCE
        return;
    }
    __shared__ float hr[D], qrow[D], krow[D], vpart[2][D], scr[4];
    int s = blockIdx.x;
    int col = t & 127, half = t >> 7, dlo = half * 64;
    // embed gather (critical path) issued first
    float xv = 0.f;
    if (t < 128) xv = sigm(w_raw[t * V + idx[s]]);
    // prefetch QKV weight columns into registers (pure tid function)
    float wpre[128];
    const float* wsel = (t < 128) ? wq : wk;
    #pragma unroll
    for (int d = 0; d < 128; ++d) wpre[d] = wsel[d * D + col];
    float wvpre[64];
    #pragma unroll
    for (int d = 0; d < 64; ++d) wvpre[d] = wv[(dlo + d) * D + col];
    if (t < 128) x[s * D + t] = xv;
    float ss = block_sum256(xv * xv, scr);
    float r = 1.0f / sqrtf(ss * (1.0f / D) + EPS);
    if (t < 128) hr[t] = xv * r * n1w[t];
    __syncthreads();
    float a0 = 0, a1 = 0, a2 = 0, a3 = 0;
    #pragma unroll
    for (int d = 0; d < 128; d += 4) {
        a0 += hr[d] * wpre[d];
        a1 += hr[d + 1] * wpre[d + 1];
        a2 += hr[d + 2] * wpre[d + 2];
        a3 += hr[d + 3] * wpre[d + 3];
    }
    float qk = (a0 + a1) + (a2 + a3);
    float b0 = 0, b1 = 0, b2 = 0, b3 = 0;
    #pragma unroll
    for (int d = 0; d < 64; d += 4) {
        b0 += hr[dlo + d] * wvpre[d];
        b1 += hr[dlo + d + 1] * wvpre[d + 1];
        b2 += hr[dlo + d + 2] * wvpre[d + 2];
        b3 += hr[dlo + d + 3] * wvpre[d + 3];
    }
    vpart[half][col] = (b0 + b1) + (b2 + b3);
    if (t < 128) qrow[col] = qk;
    else krow[col] = qk;
    __syncthreads();
    if (t < 128) {
        v[s * D + t] = vpart[0][t] + vpart[1][t];
        int c = t & (HD - 1);
        int m = c >> 1;
        float fr = (float)s * expf(-(float)m * 1.15129254649702283e+00f);
        float cs = cosf(fr), sn = sinf(fr);
        int base = t & ~1;
        float qe = qrow[base], qod = qrow[base + 1];
        float ke = krow[base], kod = krow[base + 1];
        q[s * D + t] = (c & 1) ? (qe * sn + qod * cs) : (qe * cs - qod * sn);
        k[s * D + t] = (c & 1) ? (ke * sn + kod * cs) : (ke * cs - kod * sn);
    }
}

// K2/K3: fused layer per row. grid=SEQ, block=256
template <int MODE>
__global__ __launch_bounds__(256, 1) void k_layer(
    const float* __restrict__ q, const float* __restrict__ kg,
    const float* __restrict__ vg, float* __restrict__ x,
    const float* __restrict__ wo, const float* __restrict__ n2w,
    const float* __restrict__ w1, const float* __restrict__ w3,
    const float* __restrict__ w2, const float* __restrict__ wq,
    const float* __restrict__ wk, const float* __restrict__ wv,
    const float* __restrict__ n1w, float* __restrict__ qo, float* __restrict__ ko,
    float* __restrict__ vo, const float* __restrict__ fw, float* __restrict__ xng) {
    __shared__ float ps[NH][SEQ + 1];
    __shared__ float qs[D], orow[D], h2[D];
    __shared__ float part[2][D];
    __shared__ float afA[HID], afB[HID], af[HID];
    __shared__ float rl[NH];
    __shared__ float scr[4];
    int s = blockIdx.x, t = threadIdx.x;
    int col = t & 127, half = t >> 7;
    int jlo = half * 64, dlo = half * 64;

    // activation loads first (critical path)
    float qv = 0.f, xr = 0.f;
    if (t < 128) {
        qv = q[s * D + t];
        xr = x[s * D + t];
    }
    // register prefetch: K slices (scores), V (o-stage), wo — pending across barriers
    float4 kp[4][4];
    #pragma unroll
    for (int u = 0; u < 4; ++u) {
        const float4* p = (const float4*)&kg[col * D + (half + 2 * u) * HD];
        kp[u][0] = p[0]; kp[u][1] = p[1]; kp[u][2] = p[2]; kp[u][3] = p[3];
    }
    float vpre[64];
    #pragma unroll
    for (int j = 0; j < 64; ++j) vpre[j] = vg[(jlo + j) * D + col];
    float wopre[64];
    #pragma unroll
    for (int u = 0; u < 64; ++u) wopre[u] = wo[(dlo + u) * D + col];

    if (t < 128) qs[t] = qv;
    __syncthreads();

    // scores: thread (j=col, h=half+2u); zero-fill j>s so o-stage is unconditional
    #pragma unroll
    for (int u = 0; u < 4; ++u) {
        int h = half + 2 * u;
        const float* qh = &qs[h * HD];
        float acc = kp[u][0].x * qh[0] + kp[u][0].y * qh[1] + kp[u][0].z * qh[2] +
                    kp[u][0].w * qh[3] + kp[u][1].x * qh[4] + kp[u][1].y * qh[5] +
                    kp[u][1].z * qh[6] + kp[u][1].w * qh[7] + kp[u][2].x * qh[8] +
                    kp[u][2].y * qh[9] + kp[u][2].z * qh[10] + kp[u][2].w * qh[11] +
                    kp[u][3].x * qh[12] + kp[u][3].y * qh[13] + kp[u][3].z * qh[14] +
                    kp[u][3].w * qh[15];
        ps[h][col] = (col <= s) ? acc * 0.25f : 0.f;
    }
    __syncthreads();

    // softmax over j<=s: head h = t>>5, 32 lanes each
    {
        int h = t >> 5, lane = t & 31;
        float pm = -1e30f;
        for (int j = lane; j <= s; j += 32) pm = fmaxf(pm, ps[h][j]);
        #pragma unroll
        for (int m = 16; m > 0; m >>= 1) pm = fmaxf(pm, __shfl_xor(pm, m, 32));
        float psum = 0.f;
        for (int j = lane; j <= s; j += 32) {
            float e = __expf(ps[h][j] - pm);
            ps[h][j] = e;
            psum += e;
        }
        #pragma unroll
        for (int m = 16; m > 0; m >>= 1) psum += __shfl_xor(psum, m, 32);
        if (lane == 0) rl[h] = 1.0f / psum;
    }
    __syncthreads();

    // o partials from prefetched V (ps zero beyond s)
    {
        int h = col >> 4;
        float a0 = 0, a1 = 0, a2 = 0, a3 = 0;
        #pragma unroll
        for (int j = 0; j < 64; j += 4) {
            a0 += ps[h][jlo + j] * vpre[j];
            a1 += ps[h][jlo + j + 1] * vpre[j + 1];
            a2 += ps[h][jlo + j + 2] * vpre[j + 2];
            a3 += ps[h][jlo + j + 3] * vpre[j + 3];
        }
        part[half][col] = (a0 + a1) + (a2 + a3);
    }
    __syncthreads();
    if (t < 128) orow[t] = (part[0][t] + part[1][t]) * rl[t >> 4];
    __syncthreads();

    // wo from prefetched registers
    {
        float a0 = 0, a1 = 0;
        #pragma unroll
        for (int u = 0; u < 64; u += 2) {
            a0 += orow[dlo + u] * wopre[u];
            a1 += orow[dlo + u + 1] * wopre[u + 1];
        }
        part[half][col] = a0 + a1;
    }
    __syncthreads();
    float xn = 0.f;
    if (t < 128) xn = xr + part[0][t] + part[1][t];
    float ss2 = block_sum256((t < 128) ? xn * xn : 0.f, scr);
    float r2 = 1.0f / sqrtf(ss2 * (1.0f / D) + EPS);
    if (t < 128) h2[t] = xn * r2 * n2w[t];
    __syncthreads();

    // FFN1: 682 column-tasks, 32 loads in flight
    for (int task = t; task < 2 * HID; task += 256) {
        int mat = task >= HID;
        int c2 = mat ? (task - HID) : task;
        const float* w = mat ? w3 : w1;
        float a0 = 0, a1 = 0, a2 = 0, a3 = 0;
        #pragma unroll 8
        for (int d = 0; d < D; d += 4) {
            a0 += h2[d] * w[d * HID + c2];
            a1 += h2[d + 1] * w[(d + 1) * HID + c2];
            a2 += h2[d + 2] * w[(d + 2) * HID + c2];
            a3 += h2[d + 3] * w[(d + 3) * HID + c2];
        }
        if (mat) afB[c2] = (a0 + a1) + (a2 + a3);
        else afA[c2] = (a0 + a1) + (a2 + a3);
    }
    __syncthreads();
    for (int c2 = t; c2 < HID; c2 += 256) {
        float a1v = afA[c2];
        af[c2] = (a1v / (1.0f + __expf(-a1v))) * afB[c2];
    }
    __syncthreads();

    // FFN2: col output, 341-sum split [0,171)/[171,341)
    {
        int lo = half ? 171 : 0;
        int hi = half ? 341 : 171;
        float a0 = 0, a1 = 0, a2 = 0, a3 = 0;
        int tt = lo;
        #pragma unroll 8
        for (; tt + 3 < hi; tt += 4) {
            a0 += af[tt] * w2[tt * D + col];
            a1 += af[tt + 1] * w2[(tt + 1) * D + col];
            a2 += af[tt + 2] * w2[(tt + 2) * D + col];
            a3 += af[tt + 3] * w2[(tt + 3) * D + col];
        }
        for (; tt < hi; ++tt) a0 += af[tt] * w2[tt * D + col];
        part[half][col] = (a0 + a1) + (a2 + a3);
    }
    __syncthreads();
    float x2 = 0.f;
    if (t < 128) {
        x2 = xn + part[0][t] + part[1][t];
        if (MODE == 0) x[s * D + t] = x2;
    }

    float ss = block_sum256((t < 128) ? x2 * x2 : 0.f, scr);
    float r = 1.0f / sqrtf(ss * (1.0f / D) + EPS);

    if constexpr (MODE == 0) {
        if (t < 128) h2[t] = x2 * r * n1w[t];
        __syncthreads();
        // next-layer QKV (streamed, 32 in flight) + rope
        const float* wsel = (t < 128) ? wq : wk;
        float a0 = 0, a1 = 0, a2 = 0, a3 = 0;
        #pragma unroll 8
        for (int d = 0; d < D; d += 4) {
            a0 += h2[d] * wsel[d * D + col];
            a1 += h2[d + 1] * wsel[(d + 1) * D + col];
            a2 += h2[d + 2] * wsel[(d + 2) * D + col];
            a3 += h2[d + 3] * wsel[(d + 3) * D + col];
        }
        float qk = (a0 + a1) + (a2 + a3);
        float b0 = 0, b1 = 0, b2 = 0, b3 = 0;
        #pragma unroll 8
        for (int d = dlo; d < dlo + 64; d += 4) {
            b0 += h2[d] * wv[d * D + col];
            b1 += h2[d + 1] * wv[(d + 1) * D + col];
            b2 += h2[d + 2] * wv[(d + 2) * D + col];
            b3 += h2[d + 3] * wv[(d + 3) * D + col];
        }
        part[half][col] = (b0 + b1) + (b2 + b3);
        if (t < 128) qs[col] = qk;
        else orow[col] = qk;
        __syncthreads();
        if (t < 128) {
            vo[s * D + t] = part[0][t] + part[1][t];
            int c = t & (HD - 1);
            int mm = c >> 1;
            float fr = (float)s * expf(-(float)mm * 1.15129254649702283e+00f);
            float cs = cosf(fr), sn = sinf(fr);
            int base = t & ~1;
            float qe = qs[base], qod = qs[base + 1];
            float ke = orow[base], kod = orow[base + 1];
            qo[s * D + t] = (c & 1) ? (qe * sn + qod * cs) : (qe * cs - qod * sn);
            ko[s * D + t] = (c & 1) ? (ke * sn + kod * cs) : (ke * cs - kod * sn);
        }
    } else {
        float y = (t < 128) ? x2 * r * fw[t] : 0.f;
        float nn = block_sum256(y * y, scr);
        if (t < 128) xng[t * SEQ + s] = y / sqrtf(nn);
    }
}

// K4: logits[s,v] = clip(mean_d(xn[s,d] <= vn[v,d] ? 1 : vn[v,d]))
__global__ __launch_bounds__(256) void k_logits(const float* __restrict__ xng,
                                                const float* __restrict__ w_raw,
                                                float* __restrict__ out) {
    __shared__ float xs[D * 64];
    __shared__ float vs[D * 32];
    __shared__ float nred[256];
    __shared__ float invn_s[32];
    int t = threadIdx.x;
    int sbase = (blockIdx.x & 1) * 64;
    int vbase = (blockIdx.x >> 1) * 32;
    for (int i = t; i < D * 64; i += 256) {
        int d = i >> 6, s2 = i & 63;
        xs[i] = xng[d * SEQ + sbase + s2];
    }
    for (int i = t; i < D * 32; i += 256) {
        int d = i >> 5, jj = i & 31;
        vs[i] = sigm(w_raw[d * V + vbase + jj]);
    }
    __syncthreads();
    {
        int colc = t & 31, dp = t >> 5;
        float p = 0.f;
        for (int u = 0; u < 16; ++u) {
            float vv = vs[(dp * 16 + u) * 32 + colc];
            p += vv * vv;
        }
        nred[t] = p;
    }
    __syncthreads();
    if (t < 32) {
        float sum = 0.f;
        for (int u = 0; u < 8; ++u) sum += nred[u * 32 + t];
        invn_s[t] = 1.0f / sqrtf(sum);
    }
    __syncthreads();
    for (int i = t; i < D * 32; i += 256) vs[i] *= invn_s[i & 31];
    __syncthreads();
    int vg = t & 15;
    int sg = t >> 4;
    float acc[4][2] = {};
    for (int d = 0; d < D; ++d) {
        float4 xq = *(const float4*)&xs[d * 64 + sg * 4];
        float2 vq = *(const float2*)&vs[d * 32 + vg * 2];
        acc[0][0] += (xq.x <= vq.x) ? 1.0f : vq.x;
        acc[0][1] += (xq.x <= vq.y) ? 1.0f : vq.y;
        acc[1][0] += (xq.y <= vq.x) ? 1.0f : vq.x;
        acc[1][1] += (xq.y <= vq.y) ? 1.0f : vq.y;
        acc[2][0] += (xq.z <= vq.x) ? 1.0f : vq.x;
        acc[2][1] += (xq.z <= vq.y) ? 1.0f : vq.y;
        acc[3][0] += (xq.w <= vq.x) ? 1.0f : vq.x;
        acc[3][1] += (xq.w <= vq.y) ? 1.0f : vq.y;
    }
    const float inv128 = 1.0f / 128.0f;
    #pragma unroll
    for (int si = 0; si < 4; ++si) {
        int s = sbase + sg * 4 + si;
        float2 ov;
        ov.x = fminf(fmaxf(acc[si][0] * inv128, 1e-6f), 1.0f - 1e-6f);
        ov.y = fminf(fmaxf(acc[si][1] * inv128, 1e-6f), 1.0f - 1e-6f);
        *(float2*)&out[s * V + vbase + vg * 2] = ov;
    }
}

extern "C" void kernel_launch(void* const* d_in, const int* in_sizes, int n_in,
                              void* d_out, int out_size, void* d_ws, size_t ws_size,
                              hipStream_t stream) {
    const int* idx = (const int*)d_in[0];
    const float* w_raw = (const float*)d_in[1];
    const float* n1w = (const float*)d_in[2];
    const float* n2w = (const float*)d_in[3];
    const float* wq = (const float*)d_in[4];
    const float* wk = (const float*)d_in[5];
    const float* wv = (const float*)d_in[6];
    const float* wo = (const float*)d_in[7];
    const float* w1 = (const float*)d_in[8];
    const float* w3 = (const float*)d_in[9];
    const float* w2 = (const float*)d_in[10];
    const float* fnw = (const float*)d_in[11];
    float* out = (float*)d_out;
    float* ws = (float*)d_ws;

    float* x    = ws;
    float* q1   = ws + 16384;
    float* k1   = ws + 32768;
    float* v1   = ws + 49152;
    float* q2   = ws + 65536;
    float* k2   = ws + 81920;
    float* v2   = ws + 98304;
    float* xng  = ws + 114688;
    float* sink = ws + 131072;

    k_embed_qkv<<<dim3(SEQ + 256), dim3(256), 0, stream>>>(
        idx, w_raw, wq, wk, wv, n1w, w1, w3, w2, wo, x, q1, k1, v1, sink);
    k_layer<0><<<dim3(SEQ), dim3(256), 0, stream>>>(
        q1, k1, v1, x, wo, n2w, w1, w3, w2,
        wq + D * D, wk + D * D, wv + D * D, n1w + D, q2, k2, v2,
        (const float*)nullptr, (float*)nullptr);
    k_layer<1><<<dim3(SEQ), dim3(256), 0, stream>>>(
        q2, k2, v2, x, wo + D * D, n2w + D, w1 + D * HID, w3 + D * HID,
        w2 + HID * D, (const float*)nullptr, (const float*)nullptr,
        (const float*)nullptr, (const float*)nullptr, (float*)nullptr,
        (float*)nullptr, (float*)nullptr, fnw, xng);
    k_logits<<<dim3(512), dim3(256), 0, stream>>>(xng, w_raw, out);
}

// Round 10
// 141.518 us; speedup vs baseline: 1.0341x; 1.0341x over previous
//
#include <hip/hip_runtime.h>
#include <math.h>

#define V 8192
#define D 128
#define NH 8
#define HD 16
#define SEQ 128
#define HID 341
#define EPS 1e-6f

__device__ __forceinline__ float sigm(float x) { return 1.0f / (1.0f + __expf(-x)); }

// 256-thread block-wide sum. scratch >= 4 floats. 2 barriers.
__device__ __forceinline__ float block_sum256(float v, float* scratch) {
    #pragma unroll
    for (int m = 32; m > 0; m >>= 1) v += __shfl_xor(v, m);
    if ((threadIdx.x & 63) == 0) scratch[threadIdx.x >> 6] = v;
    __syncthreads();
    float s = (scratch[0] + scratch[1]) + (scratch[2] + scratch[3]);
    __syncthreads();
    return s;
}

// 512-thread block-wide sum. scratch >= 8 floats. 2 barriers.
__device__ __forceinline__ float block_sum512(float v, float* scratch) {
    #pragma unroll
    for (int m = 32; m > 0; m >>= 1) v += __shfl_xor(v, m);
    if ((threadIdx.x & 63) == 0) scratch[threadIdx.x >> 6] = v;
    __syncthreads();
    float s = ((scratch[0] + scratch[1]) + (scratch[2] + scratch[3])) +
              ((scratch[4] + scratch[5]) + (scratch[6] + scratch[7]));
    __syncthreads();
    return s;
}

// K1: embed + rms + qkv + rope. grid = SEQ + 256 (warm blocks), block=256
__global__ __launch_bounds__(256, 1) void k_embed_qkv(
    const int* __restrict__ idx, const float* __restrict__ w_raw,
    const float* __restrict__ wq, const float* __restrict__ wk,
    const float* __restrict__ wv, const float* __restrict__ n1w,
    const float* __restrict__ w1, const float* __restrict__ w3,
    const float* __restrict__ w2, const float* __restrict__ wo,
    float* __restrict__ x, float* __restrict__ q, float* __restrict__ k,
    float* __restrict__ v, float* __restrict__ sink) {
    int t = threadIdx.x;
    if (blockIdx.x >= SEQ) {
        // L3-warm: stream every weight once (w_raw 4MB + layers ~1.8MB)
        int g = (blockIdx.x - SEQ) * 256 + t;  // 0..65535
        float acc = 0.f;
        const float4* p = (const float4*)w_raw;  // 262144 float4
        for (int i = g; i < 262144; i += 65536) {
            float4 u = p[i];
            acc += u.x + u.y + u.z + u.w;
        }
        p = (const float4*)w1;  // 21824 float4 (both layers)
        if (g < 21824) { float4 u = p[g]; acc += u.x + u.y + u.z + u.w; }
        p = (const float4*)w3;
        if (g < 21824) { float4 u = p[g]; acc += u.x + u.y + u.z + u.w; }
        p = (const float4*)w2;
        if (g < 21824) { float4 u = p[g]; acc += u.x + u.y + u.z + u.w; }
        p = (const float4*)wq;  // 8192 float4 (both layers)
        if (g < 8192) { float4 u = p[g]; acc += u.x + u.y + u.z + u.w; }
        p = (const float4*)wk;
        if (g < 8192) { float4 u = p[g]; acc += u.x + u.y + u.z + u.w; }
        p = (const float4*)wv;
        if (g < 8192) { float4 u = p[g]; acc += u.x + u.y + u.z + u.w; }
        p = (const float4*)wo;
        if (g < 8192) { float4 u = p[g]; acc += u.x + u.y + u.z + u.w; }
        if (acc == 1234.5678f) sink[0] = acc;  // never true; defeats DCE
        return;
    }
    __shared__ float hr[D], qrow[D], krow[D], vpart[2][D], scr[4];
    int s = blockIdx.x;
    int col = t & 127, half = t >> 7, dlo = half * 64;
    // embed gather (critical path) issued first
    float xv = 0.f;
    if (t < 128) xv = sigm(w_raw[t * V + idx[s]]);
    // prefetch QKV weight columns into registers (pure tid function)
    float wpre[128];
    const float* wsel = (t < 128) ? wq : wk;
    #pragma unroll
    for (int d = 0; d < 128; ++d) wpre[d] = wsel[d * D + col];
    float wvpre[64];
    #pragma unroll
    for (int d = 0; d < 64; ++d) wvpre[d] = wv[(dlo + d) * D + col];
    if (t < 128) x[s * D + t] = xv;
    float ss = block_sum256(xv * xv, scr);
    float r = 1.0f / sqrtf(ss * (1.0f / D) + EPS);
    if (t < 128) hr[t] = xv * r * n1w[t];
    __syncthreads();
    float a0 = 0, a1 = 0, a2 = 0, a3 = 0;
    #pragma unroll
    for (int d = 0; d < 128; d += 4) {
        a0 += hr[d] * wpre[d];
        a1 += hr[d + 1] * wpre[d + 1];
        a2 += hr[d + 2] * wpre[d + 2];
        a3 += hr[d + 3] * wpre[d + 3];
    }
    float qk = (a0 + a1) + (a2 + a3);
    float b0 = 0, b1 = 0, b2 = 0, b3 = 0;
    #pragma unroll
    for (int d = 0; d < 64; d += 4) {
        b0 += hr[dlo + d] * wvpre[d];
        b1 += hr[dlo + d + 1] * wvpre[d + 1];
        b2 += hr[dlo + d + 2] * wvpre[d + 2];
        b3 += hr[dlo + d + 3] * wvpre[d + 3];
    }
    vpart[half][col] = (b0 + b1) + (b2 + b3);
    if (t < 128) qrow[col] = qk;
    else krow[col] = qk;
    __syncthreads();
    if (t < 128) {
        v[s * D + t] = vpart[0][t] + vpart[1][t];
        int c = t & (HD - 1);
        int m = c >> 1;
        float fr = (float)s * expf(-(float)m * 1.15129254649702283e+00f);
        float cs = cosf(fr), sn = sinf(fr);
        int base = t & ~1;
        float qe = qrow[base], qod = qrow[base + 1];
        float ke = krow[base], kod = krow[base + 1];
        q[s * D + t] = (c & 1) ? (qe * sn + qod * cs) : (qe * cs - qod * sn);
        k[s * D + t] = (c & 1) ? (ke * sn + kod * cs) : (ke * cs - kod * sn);
    }
}

// K2/K3: fused layer per row. grid=SEQ, block=512 (8 waves, 2 waves/SIMD)
template <int MODE>
__global__ __launch_bounds__(512, 2) void k_layer(
    const float* __restrict__ q, const float* __restrict__ kg,
    const float* __restrict__ vg, float* __restrict__ x,
    const float* __restrict__ wo, const float* __restrict__ n2w,
    const float* __restrict__ w1, const float* __restrict__ w3,
    const float* __restrict__ w2, const float* __restrict__ wq,
    const float* __restrict__ wk, const float* __restrict__ wv,
    const float* __restrict__ n1w, float* __restrict__ qo, float* __restrict__ ko,
    float* __restrict__ vo, const float* __restrict__ fw, float* __restrict__ xng) {
    __shared__ float ps[NH][SEQ + 1];
    __shared__ float qs[D], orow[D], h2[D];
    __shared__ float part[4][D];
    __shared__ float afA[HID], afB[HID], af[HID];
    __shared__ float rl[NH];
    __shared__ float scr[8];
    int s = blockIdx.x, t = threadIdx.x;
    int col = t & 127, quarter = t >> 7;  // quarter in 0..3
    int jlo = quarter * 32, dlo = quarter * 32;

    // activation loads first (critical path)
    float qv = 0.f, xr = 0.f;
    if (t < 128) {
        qv = q[s * D + t];
        xr = x[s * D + t];
    }
    // register prefetch: K slices (scores), V (o-stage), wo — pending across barriers
    float4 kp[2][4];
    #pragma unroll
    for (int u = 0; u < 2; ++u) {
        const float4* p = (const float4*)&kg[col * D + (quarter + 4 * u) * HD];
        kp[u][0] = p[0]; kp[u][1] = p[1]; kp[u][2] = p[2]; kp[u][3] = p[3];
    }
    float vpre[32];
    #pragma unroll
    for (int j = 0; j < 32; ++j) vpre[j] = vg[(jlo + j) * D + col];
    float wopre[32];
    #pragma unroll
    for (int u = 0; u < 32; ++u) wopre[u] = wo[(dlo + u) * D + col];

    if (t < 128) qs[t] = qv;
    __syncthreads();

    // scores: thread (j=col, h=quarter+4u); zero-fill j>s so o-stage is unconditional
    #pragma unroll
    for (int u = 0; u < 2; ++u) {
        int h = quarter + 4 * u;
        const float* qh = &qs[h * HD];
        float acc = kp[u][0].x * qh[0] + kp[u][0].y * qh[1] + kp[u][0].z * qh[2] +
                    kp[u][0].w * qh[3] + kp[u][1].x * qh[4] + kp[u][1].y * qh[5] +
                    kp[u][1].z * qh[6] + kp[u][1].w * qh[7] + kp[u][2].x * qh[8] +
                    kp[u][2].y * qh[9] + kp[u][2].z * qh[10] + kp[u][2].w * qh[11] +
                    kp[u][3].x * qh[12] + kp[u][3].y * qh[13] + kp[u][3].z * qh[14] +
                    kp[u][3].w * qh[15];
        ps[h][col] = (col <= s) ? acc * 0.25f : 0.f;
    }
    __syncthreads();

    // softmax over j<=s: head h = t>>6, one full wave (64 lanes) per head
    {
        int h = t >> 6, lane = t & 63;
        float pm = -1e30f;
        for (int j = lane; j <= s; j += 64) pm = fmaxf(pm, ps[h][j]);
        #pragma unroll
        for (int m = 32; m > 0; m >>= 1) pm = fmaxf(pm, __shfl_xor(pm, m));
        float psum = 0.f;
        for (int j = lane; j <= s; j += 64) {
            float e = __expf(ps[h][j] - pm);
            ps[h][j] = e;
            psum += e;
        }
        #pragma unroll
        for (int m = 32; m > 0; m >>= 1) psum += __shfl_xor(psum, m);
        if (lane == 0) rl[h] = 1.0f / psum;
    }
    __syncthreads();

    // o partials from prefetched V (ps zero beyond s), 4-way j-split
    {
        int h = col >> 4;
        float a0 = 0, a1 = 0, a2 = 0, a3 = 0;
        #pragma unroll
        for (int j = 0; j < 32; j += 4) {
            a0 += ps[h][jlo + j] * vpre[j];
            a1 += ps[h][jlo + j + 1] * vpre[j + 1];
            a2 += ps[h][jlo + j + 2] * vpre[j + 2];
            a3 += ps[h][jlo + j + 3] * vpre[j + 3];
        }
        part[quarter][col] = (a0 + a1) + (a2 + a3);
    }
    __syncthreads();
    if (t < 128) orow[t] = ((part[0][t] + part[1][t]) + (part[2][t] + part[3][t])) * rl[t >> 4];
    __syncthreads();

    // wo from prefetched registers, 4-way u-split
    {
        float a0 = 0, a1 = 0;
        #pragma unroll
        for (int u = 0; u < 32; u += 2) {
            a0 += orow[dlo + u] * wopre[u];
            a1 += orow[dlo + u + 1] * wopre[u + 1];
        }
        part[quarter][col] = a0 + a1;
    }
    __syncthreads();
    float xn = 0.f;
    if (t < 128) xn = xr + (part[0][t] + part[1][t]) + (part[2][t] + part[3][t]);
    float ss2 = block_sum512((t < 128) ? xn * xn : 0.f, scr);
    float r2 = 1.0f / sqrtf(ss2 * (1.0f / D) + EPS);
    if (t < 128) h2[t] = xn * r2 * n2w[t];
    __syncthreads();

    // FFN1: 682 column-tasks over 512 threads (2 rounds)
    for (int task = t; task < 2 * HID; task += 512) {
        int mat = task >= HID;
        int c2 = mat ? (task - HID) : task;
        const float* w = mat ? w3 : w1;
        float a0 = 0, a1 = 0, a2 = 0, a3 = 0;
        #pragma unroll 8
        for (int d = 0; d < D; d += 4) {
            a0 += h2[d] * w[d * HID + c2];
            a1 += h2[d + 1] * w[(d + 1) * HID + c2];
            a2 += h2[d + 2] * w[(d + 2) * HID + c2];
            a3 += h2[d + 3] * w[(d + 3) * HID + c2];
        }
        if (mat) afB[c2] = (a0 + a1) + (a2 + a3);
        else afA[c2] = (a0 + a1) + (a2 + a3);
    }
    __syncthreads();
    if (t < HID) {
        float a1v = afA[t];
        af[t] = (a1v / (1.0f + __expf(-a1v))) * afB[t];
    }
    __syncthreads();

    // FFN2: col output, 341-sum split 4-way: [0,85)/[85,170)/[170,255)/[255,341)
    {
        int lo = quarter * 85;
        int hi = (quarter == 3) ? 341 : lo + 85;
        float a0 = 0, a1 = 0, a2 = 0, a3 = 0;
        int tt = lo;
        #pragma unroll 8
        for (; tt + 3 < hi; tt += 4) {
            a0 += af[tt] * w2[tt * D + col];
            a1 += af[tt + 1] * w2[(tt + 1) * D + col];
            a2 += af[tt + 2] * w2[(tt + 2) * D + col];
            a3 += af[tt + 3] * w2[(tt + 3) * D + col];
        }
        for (; tt < hi; ++tt) a0 += af[tt] * w2[tt * D + col];
        part[quarter][col] = (a0 + a1) + (a2 + a3);
    }
    __syncthreads();
    float x2 = 0.f;
    if (t < 128) {
        x2 = xn + (part[0][t] + part[1][t]) + (part[2][t] + part[3][t]);
        if (MODE == 0) x[s * D + t] = x2;
    }

    float ss = block_sum512((t < 128) ? x2 * x2 : 0.f, scr);
    float r = 1.0f / sqrtf(ss * (1.0f / D) + EPS);

    if constexpr (MODE == 0) {
        if (t < 128) h2[t] = x2 * r * n1w[t];
        __syncthreads();
        // next-layer QKV: group 0=q, 1=k, 2=v (full 128-deep dots), group 3 idle
        float qk = 0.f;
        if (quarter < 3) {
            const float* wsel = (quarter == 0) ? wq : ((quarter == 1) ? wk : wv);
            float a0 = 0, a1 = 0, a2 = 0, a3 = 0;
            #pragma unroll 8
            for (int d = 0; d < D; d += 4) {
                a0 += h2[d] * wsel[d * D + col];
                a1 += h2[d + 1] * wsel[(d + 1) * D + col];
                a2 += h2[d + 2] * wsel[(d + 2) * D + col];
                a3 += h2[d + 3] * wsel[(d + 3) * D + col];
            }
            qk = (a0 + a1) + (a2 + a3);
        }
        if (quarter == 0) qs[col] = qk;
        else if (quarter == 1) orow[col] = qk;
        else if (quarter == 2) part[0][col] = qk;
        __syncthreads();
        if (t < 128) {
            vo[s * D + t] = part[0][t];
            int c = t & (HD - 1);
            int mm = c >> 1;
            float fr = (float)s * expf(-(float)mm * 1.15129254649702283e+00f);
            float cs = cosf(fr), sn = sinf(fr);
            int base = t & ~1;
            float qe = qs[base], qod = qs[base + 1];
            float ke = orow[base], kod = orow[base + 1];
            qo[s * D + t] = (c & 1) ? (qe * sn + qod * cs) : (qe * cs - qod * sn);
            ko[s * D + t] = (c & 1) ? (ke * sn + kod * cs) : (ke * cs - kod * sn);
        }
    } else {
        float y = (t < 128) ? x2 * r * fw[t] : 0.f;
        float nn = block_sum512(y * y, scr);
        if (t < 128) xng[t * SEQ + s] = y / sqrtf(nn);
    }
}

// K4: logits[s,v] = clip(mean_d(xn[s,d] <= vn[v,d] ? 1 : vn[v,d]))
__global__ __launch_bounds__(256) void k_logits(const float* __restrict__ xng,
                                                const float* __restrict__ w_raw,
                                                float* __restrict__ out) {
    __shared__ float xs[D * 64];
    __shared__ float vs[D * 32];
    __shared__ float nred[256];
    __shared__ float invn_s[32];
    int t = threadIdx.x;
    int sbase = (blockIdx.x & 1) * 64;
    int vbase = (blockIdx.x >> 1) * 32;
    for (int i = t; i < D * 64; i += 256) {
        int d = i >> 6, s2 = i & 63;
        xs[i] = xng[d * SEQ + sbase + s2];
    }
    for (int i = t; i < D * 32; i += 256) {
        int d = i >> 5, jj = i & 31;
        vs[i] = sigm(w_raw[d * V + vbase + jj]);
    }
    __syncthreads();
    {
        int colc = t & 31, dp = t >> 5;
        float p = 0.f;
        for (int u = 0; u < 16; ++u) {
            float vv = vs[(dp * 16 + u) * 32 + colc];
            p += vv * vv;
        }
        nred[t] = p;
    }
    __syncthreads();
    if (t < 32) {
        float sum = 0.f;
        for (int u = 0; u < 8; ++u) sum += nred[u * 32 + t];
        invn_s[t] = 1.0f / sqrtf(sum);
    }
    __syncthreads();
    for (int i = t; i < D * 32; i += 256) vs[i] *= invn_s[i & 31];
    __syncthreads();
    int vg = t & 15;
    int sg = t >> 4;
    float acc[4][2] = {};
    for (int d = 0; d < D; ++d) {
        float4 xq = *(const float4*)&xs[d * 64 + sg * 4];
        float2 vq = *(const float2*)&vs[d * 32 + vg * 2];
        acc[0][0] += (xq.x <= vq.x) ? 1.0f : vq.x;
        acc[0][1] += (xq.x <= vq.y) ? 1.0f : vq.y;
        acc[1][0] += (xq.y <= vq.x) ? 1.0f : vq.x;
        acc[1][1] += (xq.y <= vq.y) ? 1.0f : vq.y;
        acc[2][0] += (xq.z <= vq.x) ? 1.0f : vq.x;
        acc[2][1] += (xq.z <= vq.y) ? 1.0f : vq.y;
        acc[3][0] += (xq.w <= vq.x) ? 1.0f : vq.x;
        acc[3][1] += (xq.w <= vq.y) ? 1.0f : vq.y;
    }
    const float inv128 = 1.0f / 128.0f;
    #pragma unroll
    for (int si = 0; si < 4; ++si) {
        int s = sbase + sg * 4 + si;
        float2 ov;
        ov.x = fminf(fmaxf(acc[si][0] * inv128, 1e-6f), 1.0f - 1e-6f);
        ov.y = fminf(fmaxf(acc[si][1] * inv128, 1e-6f), 1.0f - 1e-6f);
        *(float2*)&out[s * V + vbase + vg * 2] = ov;
    }
}

extern "C" void kernel_launch(void* const* d_in, const int* in_sizes, int n_in,
                              void* d_out, int out_size, void* d_ws, size_t ws_size,
                              hipStream_t stream) {
    const int* idx = (const int*)d_in[0];
    const float* w_raw = (const float*)d_in[1];
    const float* n1w = (const float*)d_in[2];
    const float* n2w = (const float*)d_in[3];
    const float* wq = (const float*)d_in[4];
    const float* wk = (const float*)d_in[5];
    const float* wv = (const float*)d_in[6];
    const float* wo = (const float*)d_in[7];
    const float* w1 = (const float*)d_in[8];
    const float* w3 = (const float*)d_in[9];
    const float* w2 = (const float*)d_in[10];
    const float* fnw = (const float*)d_in[11];
    float* out = (float*)d_out;
    float* ws = (float*)d_ws;

    float* x    = ws;
    float* q1   = ws + 16384;
    float* k1   = ws + 32768;
    float* v1   = ws + 49152;
    float* q2   = ws + 65536;
    float* k2   = ws + 81920;
    float* v2   = ws + 98304;
    float* xng  = ws + 114688;
    float* sink = ws + 131072;

    k_embed_qkv<<<dim3(SEQ + 256), dim3(256), 0, stream>>>(
        idx, w_raw, wq, wk, wv, n1w, w1, w3, w2, wo, x, q1, k1, v1, sink);
    k_layer<0><<<dim3(SEQ), dim3(512), 0, stream>>>(
        q1, k1, v1, x, wo, n2w, w1, w3, w2,
        wq + D * D, wk + D * D, wv + D * D, n1w + D, q2, k2, v2,
        (const float*)nullptr, (float*)nullptr);
    k_layer<1><<<dim3(SEQ), dim3(512), 0, stream>>>(
        q2, k2, v2, x, wo + D * D, n2w + D, w1 + D * HID, w3 + D * HID,
        w2 + HID * D, (const float*)nullptr, (const float*)nullptr,
        (const float*)nullptr, (const float*)nullptr, (float*)nullptr,
        (float*)nullptr, (float*)nullptr, fnw, xng);
    k_logits<<<dim3(512), dim3(256), 0, stream>>>(xng, w_raw, out);
}